// Round 3
// baseline (1898.764 us; speedup 1.0000x reference)
//
#include <hip/hip_runtime.h>
#include <hip/hip_bf16.h>

#define NS 64
#define NV 16
#define NH 8
#define VROW 368   // 8 heads * 46

typedef __attribute__((ext_vector_type(8))) short bf16x8;
typedef __attribute__((ext_vector_type(4))) float f32x4;

__device__ inline ushort f2bf(float f){
  union { __hip_bfloat16 b; ushort u; } v;
  v.b = __float2bfloat16(f);
  return v.u;
}

// ---------- K0: init segment-max to ordered(-inf) ----------
__global__ void k_init_amax(unsigned* __restrict__ amax, int n){
  int i = blockIdx.x*256 + threadIdx.x;
  if(i<n) amax[i] = 0x007FFFFFu;
}

// ---------- K1: node transforms (64 nodes / block) ----------
__global__ __launch_bounds__(256) void k_node(
  const float* __restrict__ ni,
  const float* __restrict__ wss, const float* __restrict__ wsv,
  const float* __restrict__ wds, const float* __restrict__ wdv,
  float* __restrict__ xs_s, float* __restrict__ xs_d,
  float* __restrict__ xv_s, float* __restrict__ xv_d, int N)
{
  __shared__ float sW0[64*64], sW1[64*64];
  __shared__ float sV0[256], sV1[256];
  __shared__ float sRow[4][112];
  int t = threadIdx.x, wid = t>>6, lane = t&63;
  for(int i=t;i<4096;i+=256){ sW0[i]=wss[i]; sW1[i]=wds[i]; }
  if(t<256){ sV0[t]=wsv[t]; sV1[t]=wdv[t]; }
  __syncthreads();
  for(int itn=0; itn<16; ++itn){
    int node = blockIdx.x*64 + itn*4 + wid;
    if(node>=N) continue;
    const float* row = ni + (size_t)node*112;
    if(lane<56) ((float2*)sRow[wid])[lane] = ((const float2*)row)[lane];
    float* r = sRow[wid];
    float a0=0.f, a1=0.f;
    #pragma unroll 8
    for(int k=0;k<64;k++){ float x=r[k]; a0+=x*sW0[k*64+lane]; a1+=x*sW1[k*64+lane]; }
    xs_s[(size_t)node*64+lane]=a0; xs_d[(size_t)node*64+lane]=a1;
    if(lane<48){
      int e_=lane/3, d_=lane-e_*3; float b0=0.f, b1=0.f;
      #pragma unroll
      for(int c=0;c<16;c++){ float x=r[64+c*3+d_]; b0+=x*sV0[c*16+e_]; b1+=x*sV1[c*16+e_]; }
      xv_s[(size_t)node*48+lane]=b0; xv_d[(size_t)node*48+lane]=b1;
    }
  }
}

// ---------- K2: per-wave MFMA radial MLP + geometric features ----------
// Each wave owns a 16-edge tile; no __syncthreads in the main loop.
__global__ __launch_bounds__(256) void k_edge(
  const int* __restrict__ esrc, const int* __restrict__ edst,
  const float* __restrict__ eattr, const float* __restrict__ escal,
  const float* __restrict__ w1, const float* __restrict__ b1,
  const float* __restrict__ w2, const float* __restrict__ b2,
  const float* __restrict__ adot,
  const float* __restrict__ xs_s, const float* __restrict__ xs_d,
  const float* __restrict__ xv_s, const float* __restrict__ xv_d,
  _Float16* __restrict__ value, float* __restrict__ alpha,
  unsigned* __restrict__ amax_u, int E)
{
  __shared__ __align__(16) ushort sW1t[64*136];   // W1^T [n][k] bf16
  __shared__ __align__(16) ushort sW2t[176*72];   // W2^T [n][k] bf16
  __shared__ __align__(16) ushort sUWS[4][3200];  // per-wave: ht[16][72] bf16 / ws[16][200] f16
  __shared__ float sScrS[4][64];
  __shared__ float sScrV[4][48];
  __shared__ float sScrO[4][80];
  __shared__ float sAdot[80];
  __shared__ uchar4 sTbl[368];

  int t = threadIdx.x, wid = t>>6, lane = t&63;
  int r16 = lane&15, g = lane>>4;

  // ---- one-time staging ----
  for(int i=t;i<128*64;i+=256){ int k=i>>6, n=i&63; sW1t[n*136+k]=f2bf(w1[i]); }
  for(int i=t;i<64*176;i+=256){ int k=i/176, n=i-k*176; sW2t[n*72+k]=f2bf(w2[i]); }
  if(t<80) sAdot[t]=adot[t];
  for(int j=t;j<368;j+=256){
    int hh=j/46, c=j-hh*46, q=0, d=0;
    if(c>=10){ int mm=c-10; q=mm/3; d=mm-q*3; }
    sTbl[j]=make_uchar4((unsigned char)hh,(unsigned char)c,(unsigned char)q,(unsigned char)d);
  }
  __syncthreads();   // the only block-wide barrier

  // loop-invariant per-lane bias registers
  float b1v[4], b2v[11];
  #pragma unroll
  for(int nt=0;nt<4;nt++) b1v[nt]=b1[nt*16+r16];
  #pragma unroll
  for(int s=0;s<11;s++) b2v[s]=b2[s*16+r16];

  ushort* uws = sUWS[wid];
  _Float16* wsv_ = (_Float16*)uws;
  float* scrS = sScrS[wid];
  float* scrV = sScrV[wid];
  float* scrO = sScrO[wid];

  int ntiles = (E+15)>>4;
  int nwaves = gridDim.x*4;

  for(int wt = blockIdx.x*4+wid; wt < ntiles; wt += nwaves){
    int ebase = wt*16;
    int erow = ebase + r16; if(erow >= E) erow = E-1;

    // ---- GEMM1: mid[16][64] = es @ W1, es loaded global->regs ----
    f32x4 acc[4];
    #pragma unroll
    for(int nt=0;nt<4;nt++) acc[nt]=(f32x4){0,0,0,0};
    #pragma unroll
    for(int ks=0;ks<4;ks++){
      const float* p = escal + (size_t)erow*128 + ks*32 + g*8;
      float4 va = *(const float4*)p;
      float4 vb = *(const float4*)(p+4);
      bf16x8 af;
      af[0]=(short)f2bf(va.x); af[1]=(short)f2bf(va.y);
      af[2]=(short)f2bf(va.z); af[3]=(short)f2bf(va.w);
      af[4]=(short)f2bf(vb.x); af[5]=(short)f2bf(vb.y);
      af[6]=(short)f2bf(vb.z); af[7]=(short)f2bf(vb.w);
      #pragma unroll
      for(int nt=0;nt<4;nt++){
        bf16x8 bf = *(const bf16x8*)&sW1t[(nt*16+r16)*136 + ks*32 + g*8];
        acc[nt] = __builtin_amdgcn_mfma_f32_16x16x32_bf16(af,bf,acc[nt],0,0,0);
      }
    }

    // ---- bias + LayerNorm + silu in registers ----
    // C/D layout: col = nt*16+r16, row = g*4+q
    #pragma unroll
    for(int nt=0;nt<4;nt++)
      #pragma unroll
      for(int q=0;q<4;q++) acc[nt][q] += b1v[nt];
    #pragma unroll
    for(int q=0;q<4;q++){
      float s = acc[0][q]+acc[1][q]+acc[2][q]+acc[3][q];
      float ss = acc[0][q]*acc[0][q]+acc[1][q]*acc[1][q]+acc[2][q]*acc[2][q]+acc[3][q]*acc[3][q];
      #pragma unroll
      for(int o=1;o<16;o<<=1){ s += __shfl_xor(s,o); ss += __shfl_xor(ss,o); }
      float m = s*(1.f/64.f);
      float var = ss*(1.f/64.f) - m*m;
      float inv = rsqrtf(var + 1e-5f);
      int rr = g*4+q;
      #pragma unroll
      for(int nt=0;nt<4;nt++){
        float xn = (acc[nt][q]-m)*inv;
        float h = xn/(1.f+__expf(-xn));
        uws[rr*72 + nt*16 + r16] = f2bf(h);
      }
    }

    // ---- GEMM2: w[16][176] = h @ W2 + b2 ----
    bf16x8 af2[2];
    af2[0] = *(const bf16x8*)&uws[r16*72 + 0*32 + g*8];
    af2[1] = *(const bf16x8*)&uws[r16*72 + 1*32 + g*8];
    f32x4 c2[11];
    #pragma unroll
    for(int s=0;s<11;s++) c2[s]=(f32x4){0,0,0,0};
    #pragma unroll
    for(int ks=0;ks<2;ks++){
      #pragma unroll
      for(int s=0;s<11;s++){
        bf16x8 bf = *(const bf16x8*)&sW2t[(s*16+r16)*72 + ks*32 + g*8];
        c2[s] = __builtin_amdgcn_mfma_f32_16x16x32_bf16(af2[ks],bf,c2[s],0,0,0);
      }
    }
    // stage w rows to LDS (f16, stride 200 to break bank conflicts)
    #pragma unroll
    for(int s=0;s<11;s++){
      int col = s*16 + r16;
      #pragma unroll
      for(int q=0;q<4;q++){
        wsv_[(g*4+q)*200 + col] = (_Float16)(c2[s][q] + b2v[s]);
      }
    }

    // ---- geometric phase: 16 edges serial, lane-parallel within edge ----
    for(int el=0; el<16; ++el){
      int e = ebase + el;
      if(e >= E) break;
      const _Float16* wrow = wsv_ + el*200;
      int si = esrc[e], di = edst[e];
      float sval = xs_s[(size_t)si*64+lane] + xs_d[(size_t)di*64+lane];
      scrS[lane] = sval;
      if(lane<48) scrV[lane] = xv_s[(size_t)si*48+lane] + xv_d[(size_t)di*48+lane];
      float4 ea = *(const float4*)&eattr[(size_t)e*4];
      float e0=ea.x, e1x=ea.y, e1y=ea.z, e1z=ea.w;
      scrO[lane] = (float)wrow[lane]*sval*e0;
      if(lane<16){
        float vx=scrV[lane*3], vy=scrV[lane*3+1], vz=scrV[lane*3+2];
        float vd = vx*e1x + vy*e1y + vz*e1z;
        scrO[64+lane] = (float)wrow[144+lane]*vd*0.5773502691896258f;
      }
      if(lane<8){
        float a=0.f;
        #pragma unroll
        for(int c=0;c<10;c++){
          float x = scrO[lane*10+c];
          float sl = x*(0.2f + 0.8f/(1.f+__expf(-x)));
          a += sl*sAdot[lane*10+c];
        }
        alpha[(size_t)e*8+lane]=a;
        unsigned u=__float_as_uint(a);
        u = (u&0x80000000u) ? ~u : (u|0x80000000u);
        atomicMax(&amax_u[(size_t)di*8+lane], u);
      }
      _Float16* vrow = value + (size_t)e*VROW;
      #pragma unroll
      for(int jt=0;jt<6;jt++){
        int j = jt*64 + lane;
        if(j>=VROW) break;
        uchar4 tb = sTbl[j];
        int hh=tb.x, c=tb.y;
        float val;
        if(c<10){ val = scrO[hh*10+c]; }
        else{
          int q=tb.z, d=tb.w; int rr=hh*12+q;
          float e1d = (d==0)?e1x:((d==1)?e1y:e1z);
          if(rr<64){ val = (float)wrow[64+rr]*scrS[rr]*e1d; }
          else if(rr<80){ int k=rr-64; val = (float)wrow[128+k]*scrV[k*3+d]*e0; }
          else{
            int k=rr-80;
            float ax=scrV[k*3], ay=scrV[k*3+1], az=scrV[k*3+2];
            float cx = ay*e1z - az*e1y;
            float cy = az*e1x - ax*e1z;
            float cz = ax*e1y - ay*e1x;
            val = (float)wrow[160+k]*((d==0)?cx:(d==1)?cy:cz)*0.7071067811865475f;
          }
        }
        vrow[j] = (_Float16)val;
      }
    }
  }
}

// ---------- K3: softmax (exp + denominator) ----------
__global__ void k_soft(const int* __restrict__ edst, float* __restrict__ alpha,
                       const unsigned* __restrict__ amax_u, float* __restrict__ den, int tot)
{
  int i = blockIdx.x*256 + threadIdx.x;
  if(i>=tot) return;
  int e=i>>3, hh=i&7;
  int d_=edst[e];
  unsigned u = amax_u[(size_t)d_*8+hh];
  float mx = (u&0x80000000u) ? __uint_as_float(u^0x80000000u) : __uint_as_float(~u);
  float ex = __expf(alpha[i]-mx);
  alpha[i]=ex;
  atomicAdd(&den[(size_t)d_*8+hh], ex);
}

// ---------- K4: weighted scatter-add (wave per edge) ----------
__global__ __launch_bounds__(256) void k_agg(
  const int* __restrict__ edst, const float* __restrict__ ex,
  const _Float16* __restrict__ value, float* __restrict__ agg, int E)
{
  int wid = threadIdx.x>>6, lane = threadIdx.x&63;
  int e = blockIdx.x*4 + wid;
  if(e>=E) return;
  int d = edst[e];
  const _Float16* vrow = value + (size_t)e*VROW;
  float* arow = agg + (size_t)d*VROW;
  const float* exr = ex + (size_t)e*8;
  #pragma unroll
  for(int it=0; it<6; ++it){
    int j = it*64 + lane;
    if(j<VROW){
      int hh = (j*713)>>15;
      float v = (float)vrow[j];
      atomicAdd(&arow[j], exr[hh]*v);
    }
  }
}

// ---------- K5: normalize + output projections (64 nodes / block) ----------
__global__ __launch_bounds__(256) void k_proj(
  const float* __restrict__ agg, const float* __restrict__ den,
  const float* __restrict__ pws, const float* __restrict__ pbs,
  const float* __restrict__ pwv, float* __restrict__ out, int N)
{
  __shared__ float sWs[80*64];
  __shared__ float sWv[96*16];
  __shared__ float sA[4][VROW];
  int t=threadIdx.x, wid=t>>6, lane=t&63;
  for(int i=t;i<80*64;i+=256) sWs[i]=pws[i];
  for(int i=t;i<96*16;i+=256) sWv[i]=pwv[i];
  __syncthreads();
  for(int itn=0; itn<16; ++itn){
    int n = blockIdx.x*64 + itn*4 + wid;
    if(n>=N) continue;
    const float* arow = agg + (size_t)n*VROW;
    float* A = sA[wid];
    for(int j=lane;j<VROW;j+=64){
      int hh=j/46;
      A[j] = arow[j] / (den[(size_t)n*8+hh] + 1e-9f);
    }
    float o1 = pbs[lane];
    #pragma unroll 8
    for(int i=0;i<80;i++){
      int hh=i/10, c=i-hh*10;
      o1 += A[hh*46+c]*sWs[i*64+lane];
    }
    out[(size_t)n*112+lane]=o1;
    if(lane<48){
      int ee=lane/3, d=lane-ee*3; float o2=0.f;
      #pragma unroll 8
      for(int c=0;c<96;c++){
        int hh=c/12, q=c-hh*12;
        o2 += A[hh*46+10+q*3+d]*sWv[c*16+ee];
      }
      out[(size_t)n*112+64+lane]=o2;
    }
  }
}

extern "C" void kernel_launch(void* const* d_in, const int* in_sizes, int n_in,
                              void* d_out, int out_size, void* d_ws, size_t ws_size,
                              hipStream_t stream)
{
  const int N = in_sizes[0]/112;
  const int E = in_sizes[1];
  const float* ni    = (const float*)d_in[0];
  const int*   esrc  = (const int*)d_in[1];
  const int*   edst  = (const int*)d_in[2];
  const float* eattr = (const float*)d_in[3];
  const float* escal = (const float*)d_in[4];
  const float* wss   = (const float*)d_in[5];
  const float* wsv   = (const float*)d_in[6];
  const float* wds   = (const float*)d_in[7];
  const float* wdv   = (const float*)d_in[8];
  const float* rw1   = (const float*)d_in[9];
  const float* rb1   = (const float*)d_in[10];
  const float* rw2   = (const float*)d_in[11];
  const float* rb2   = (const float*)d_in[12];
  const float* adot  = (const float*)d_in[13];
  const float* pws   = (const float*)d_in[14];
  const float* pbs   = (const float*)d_in[15];
  const float* pwv   = (const float*)d_in[16];
  float* out = (float*)d_out;

  char* ws = (char*)d_ws;
  size_t off = 0;
  auto alloc = [&](size_t bytes)->void*{
    void* p = ws + off;
    off = (off + bytes + 255) & ~(size_t)255;
    return p;
  };
  float*    xs_s  = (float*)   alloc((size_t)N*64*4);
  float*    xs_d  = (float*)   alloc((size_t)N*64*4);
  float*    xv_s  = (float*)   alloc((size_t)N*48*4);
  float*    xv_d  = (float*)   alloc((size_t)N*48*4);
  float*    alpha = (float*)   alloc((size_t)E*8*4);
  unsigned* amax  = (unsigned*)alloc((size_t)N*8*4);
  float*    den   = (float*)   alloc((size_t)N*8*4);
  float*    agg   = (float*)   alloc((size_t)N*VROW*4);
  _Float16* value = (_Float16*)alloc((size_t)E*VROW*2);

  hipMemsetAsync(den, 0, (size_t)N*8*4, stream);
  hipMemsetAsync(agg, 0, (size_t)N*VROW*4, stream);
  k_init_amax<<<(N*8+255)/256, 256, 0, stream>>>(amax, N*8);

  k_node<<<(N+63)/64, 256, 0, stream>>>(ni, wss, wsv, wds, wdv, xs_s, xs_d, xv_s, xv_d, N);

  k_edge<<<512, 256, 0, stream>>>(esrc, edst, eattr, escal,
        rw1, rb1, rw2, rb2, adot, xs_s, xs_d, xv_s, xv_d, value, alpha, amax, E);

  k_soft<<<(E*8+255)/256, 256, 0, stream>>>(edst, alpha, amax, den, E*8);

  k_agg<<<(E+3)/4, 256, 0, stream>>>(edst, alpha, value, agg, E);

  k_proj<<<(N+63)/64, 256, 0, stream>>>(agg, den, pws, pbs, pwv, out, N);
}

// Round 4
// 990.255 us; speedup vs baseline: 1.9174x; 1.9174x over previous
//
#include <hip/hip_runtime.h>
#include <hip/hip_bf16.h>

#define VROW 368      // 8 heads * 46 (value/agg row length)
#define WST  184      // wbuf row stride in f16 (176 + 8 pad)

typedef __attribute__((ext_vector_type(8))) short bf16x8;
typedef __attribute__((ext_vector_type(4))) float f32x4;
typedef __attribute__((ext_vector_type(8))) _Float16 f16x8;

__device__ inline ushort f2bf(float f){
  union { __hip_bfloat16 b; ushort u; } v;
  v.b = __float2bfloat16(f);
  return v.u;
}

// ---------- K1: node transforms (64 nodes / block) ----------
__global__ __launch_bounds__(256) void k_node(
  const float* __restrict__ ni,
  const float* __restrict__ wss, const float* __restrict__ wsv,
  const float* __restrict__ wds, const float* __restrict__ wdv,
  float* __restrict__ xs_s, float* __restrict__ xs_d,
  float* __restrict__ xv_s, float* __restrict__ xv_d, int N)
{
  __shared__ float sW0[64*64], sW1[64*64];
  __shared__ float sV0[256], sV1[256];
  __shared__ float sRow[4][112];
  int t = threadIdx.x, wid = t>>6, lane = t&63;
  for(int i=t;i<4096;i+=256){ sW0[i]=wss[i]; sW1[i]=wds[i]; }
  if(t<256){ sV0[t]=wsv[t]; sV1[t]=wdv[t]; }
  __syncthreads();
  for(int itn=0; itn<16; ++itn){
    int node = blockIdx.x*64 + itn*4 + wid;
    if(node>=N) continue;
    const float* row = ni + (size_t)node*112;
    if(lane<56) ((float2*)sRow[wid])[lane] = ((const float2*)row)[lane];
    float* r = sRow[wid];
    float a0=0.f, a1=0.f;
    #pragma unroll 8
    for(int k=0;k<64;k++){ float x=r[k]; a0+=x*sW0[k*64+lane]; a1+=x*sW1[k*64+lane]; }
    xs_s[(size_t)node*64+lane]=a0; xs_d[(size_t)node*64+lane]=a1;
    if(lane<48){
      int e_=lane/3, d_=lane-e_*3; float b0=0.f, b1=0.f;
      #pragma unroll
      for(int c=0;c<16;c++){ float x=r[64+c*3+d_]; b0+=x*sV0[c*16+e_]; b1+=x*sV1[c*16+e_]; }
      xv_s[(size_t)node*48+lane]=b0; xv_d[(size_t)node*48+lane]=b1;
    }
  }
}

// ---------- CSR build ----------
__global__ void k_deg(const int* __restrict__ edst, int* __restrict__ deg, int E){
  int e = blockIdx.x*256 + threadIdx.x;
  if(e<E) atomicAdd(&deg[edst[e]], 1);
}

// single-block exclusive scan (N up to ~1M fine)
__global__ __launch_bounds__(256) void k_scan(
  const int* __restrict__ deg, int* __restrict__ offs, int* __restrict__ cur, int N)
{
  __shared__ int sb[256];
  __shared__ int srun;
  int t = threadIdx.x;
  if(t==0) srun = 0;
  __syncthreads();
  for(int base=0; base<N; base+=256){
    int i = base + t;
    int x = (i<N) ? deg[i] : 0;
    sb[t] = x;
    __syncthreads();
    int v = x;
    #pragma unroll
    for(int o=1;o<256;o<<=1){
      int u = (t>=o) ? sb[t-o] : 0;
      __syncthreads();
      v += u; sb[t] = v;
      __syncthreads();
    }
    int run = srun;
    if(i<N){ int ex = run + v - x; offs[i]=ex; cur[i]=ex; }
    __syncthreads();
    if(t==255) srun = run + v;
    __syncthreads();
  }
  if(t==0) offs[N] = srun;
}

__global__ void k_fill(const int* __restrict__ edst, int* __restrict__ cur,
                       int* __restrict__ pos_of, int E){
  int e = blockIdx.x*256 + threadIdx.x;
  if(e<E) pos_of[e] = atomicAdd(&cur[edst[e]], 1);
}

// ---------- K2: radial MLP (pure MFMA GEMM pipeline) ----------
// wave-per-16-edge-tile; writes w rows (f16, stride WST) to wbuf.
__global__ __launch_bounds__(256) void k_mlp(
  const float* __restrict__ escal,
  const float* __restrict__ w1, const float* __restrict__ b1,
  const float* __restrict__ w2, const float* __restrict__ b2,
  _Float16* __restrict__ wbuf, int E)
{
  __shared__ __align__(16) ushort sW1t[64*136];    // W1^T [n][k] bf16
  __shared__ __align__(16) ushort sW2t[176*72];    // W2^T [n][k] bf16
  __shared__ __align__(16) ushort ubuf[4][16*WST]; // per-wave: h[16][72] then ws[16][WST] f16
  int t = threadIdx.x, wid = t>>6, lane = t&63;
  int r16 = lane&15, g = lane>>4;

  for(int i=t;i<128*64;i+=256){ int k=i>>6, n=i&63; sW1t[n*136+k]=f2bf(w1[i]); }
  for(int i=t;i<64*176;i+=256){ int k=i/176, n=i-k*176; sW2t[n*72+k]=f2bf(w2[i]); }
  __syncthreads();

  float b1v[4], b2v[11];
  #pragma unroll
  for(int nt=0;nt<4;nt++) b1v[nt]=b1[nt*16+r16];
  #pragma unroll
  for(int s=0;s<11;s++) b2v[s]=b2[s*16+r16];

  ushort* ub = ubuf[wid];
  _Float16* wsb = (_Float16*)ub;

  int ntiles = (E+15)>>4;
  int nw = gridDim.x*4;

  for(int wt = blockIdx.x*4+wid; wt < ntiles; wt += nw){
    int ebase = wt*16;
    int erow = ebase + r16; if(erow >= E) erow = E-1;

    // GEMM1: mid[16][64] = es @ W1 (A from global, cvt to bf16)
    f32x4 acc[4];
    #pragma unroll
    for(int nt=0;nt<4;nt++) acc[nt]=(f32x4){0,0,0,0};
    #pragma unroll
    for(int ks=0;ks<4;ks++){
      const float* p = escal + (size_t)erow*128 + ks*32 + g*8;
      float4 va = *(const float4*)p;
      float4 vb = *(const float4*)(p+4);
      bf16x8 af;
      af[0]=(short)f2bf(va.x); af[1]=(short)f2bf(va.y);
      af[2]=(short)f2bf(va.z); af[3]=(short)f2bf(va.w);
      af[4]=(short)f2bf(vb.x); af[5]=(short)f2bf(vb.y);
      af[6]=(short)f2bf(vb.z); af[7]=(short)f2bf(vb.w);
      #pragma unroll
      for(int nt=0;nt<4;nt++){
        bf16x8 bf = *(const bf16x8*)&sW1t[(nt*16+r16)*136 + ks*32 + g*8];
        acc[nt] = __builtin_amdgcn_mfma_f32_16x16x32_bf16(af,bf,acc[nt],0,0,0);
      }
    }

    // bias + LayerNorm + silu in registers; h -> LDS (stride 72)
    #pragma unroll
    for(int nt=0;nt<4;nt++)
      #pragma unroll
      for(int q=0;q<4;q++) acc[nt][q] += b1v[nt];
    #pragma unroll
    for(int q=0;q<4;q++){
      float s = acc[0][q]+acc[1][q]+acc[2][q]+acc[3][q];
      float ss = acc[0][q]*acc[0][q]+acc[1][q]*acc[1][q]+acc[2][q]*acc[2][q]+acc[3][q]*acc[3][q];
      #pragma unroll
      for(int o=1;o<16;o<<=1){ s += __shfl_xor(s,o); ss += __shfl_xor(ss,o); }
      float m = s*(1.f/64.f);
      float var = ss*(1.f/64.f) - m*m;
      float inv = rsqrtf(var + 1e-5f);
      int rr = g*4+q;
      #pragma unroll
      for(int nt=0;nt<4;nt++){
        float xn = (acc[nt][q]-m)*inv;
        float h = xn/(1.f+__expf(-xn));
        ub[rr*72 + nt*16 + r16] = f2bf(h);
      }
    }

    // GEMM2: w[16][176] = h @ W2 + b2
    bf16x8 af2[2];
    af2[0] = *(const bf16x8*)&ub[r16*72 + 0*32 + g*8];
    af2[1] = *(const bf16x8*)&ub[r16*72 + 1*32 + g*8];
    f32x4 c2[11];
    #pragma unroll
    for(int s=0;s<11;s++) c2[s]=(f32x4){0,0,0,0};
    #pragma unroll
    for(int ks=0;ks<2;ks++){
      #pragma unroll
      for(int s=0;s<11;s++){
        bf16x8 bf = *(const bf16x8*)&sW2t[(s*16+r16)*72 + ks*32 + g*8];
        c2[s] = __builtin_amdgcn_mfma_f32_16x16x32_bf16(af2[ks],bf,c2[s],0,0,0);
      }
    }
    // stage ws rows (f16, stride WST) then vector-store to global
    #pragma unroll
    for(int s=0;s<11;s++){
      int col = s*16 + r16;
      #pragma unroll
      for(int q=0;q<4;q++){
        wsb[(g*4+q)*WST + col] = (_Float16)(c2[s][q] + b2v[s]);
      }
    }
    int rows = E - ebase; if(rows > 16) rows = 16;
    int nf4 = rows*(WST/8);   // float4 count
    float4* dst = (float4*)(wbuf + (size_t)ebase*WST);
    const float4* srcv = (const float4*)ub;
    for(int i=lane; i<nf4; i+=64) dst[i] = srcv[i];
  }
}

// ---------- K3: geometric phase (gathers + value/alpha in CSR order) ----------
__global__ __launch_bounds__(256) void k_geo(
  const int* __restrict__ esrc, const int* __restrict__ edst,
  const float* __restrict__ eattr, const _Float16* __restrict__ wbuf,
  const float* __restrict__ adot,
  const float* __restrict__ xs_s, const float* __restrict__ xs_d,
  const float* __restrict__ xv_s, const float* __restrict__ xv_d,
  const int* __restrict__ pos_of,
  _Float16* __restrict__ value, float* __restrict__ alphaC, int E)
{
  __shared__ float sAdot[80];
  __shared__ uchar4 sTbl[384];
  __shared__ __align__(16) _Float16 sW[4][184];
  __shared__ float sS[4][64];
  __shared__ float sV[4][48];
  __shared__ float sO[4][80];
  int t = threadIdx.x, wid = t>>6, lane = t&63;
  if(t<80) sAdot[t]=adot[t];
  for(int j=t;j<384;j+=256){
    int hh=j/46, c=(j<VROW)?(j-hh*46):255, q=0, d=0;
    if(c>=10 && c<255){ int mm=c-10; q=mm/3; d=mm-q*3; }
    sTbl[j]=make_uchar4((unsigned char)hh,(unsigned char)c,(unsigned char)q,(unsigned char)d);
  }
  __syncthreads();

  _Float16* W = sW[wid];
  float* S = sS[wid];
  float* V = sV[wid];
  float* O = sO[wid];
  int nw = gridDim.x*4;

  for(int e = blockIdx.x*4+wid; e < E; e += nw){
    int p = pos_of[e], si = esrc[e], di = edst[e];
    float4 ea = *(const float4*)&eattr[(size_t)e*4];
    if(lane<23) ((float4*)W)[lane] = ((const float4*)(wbuf + (size_t)e*WST))[lane];
    float sval = xs_s[(size_t)si*64+lane] + xs_d[(size_t)di*64+lane];
    S[lane] = sval;
    if(lane<48) V[lane] = xv_s[(size_t)si*48+lane] + xv_d[(size_t)di*48+lane];
    float e0=ea.x, e1x=ea.y, e1y=ea.z, e1z=ea.w;
    O[lane] = (float)W[lane]*sval*e0;
    if(lane<16){
      float vx=V[lane*3], vy=V[lane*3+1], vz=V[lane*3+2];
      float vd = vx*e1x + vy*e1y + vz*e1z;
      O[64+lane] = (float)W[144+lane]*vd*0.5773502691896258f;
    }
    if(lane<8){
      float a=0.f;
      #pragma unroll
      for(int c=0;c<10;c++){
        float x = O[lane*10+c];
        float sl = x*(0.2f + 0.8f/(1.f+__expf(-x)));
        a += sl*sAdot[lane*10+c];
      }
      alphaC[(size_t)p*8+lane]=a;
    }
    _Float16* vr = value + (size_t)p*VROW;
    #pragma unroll
    for(int jt=0;jt<6;jt++){
      int j = jt*64 + lane;
      if(j>=VROW) break;
      uchar4 tb = sTbl[j];
      int hh=tb.x, c=tb.y;
      float val;
      if(c<10){ val = O[hh*10+c]; }
      else{
        int q=tb.z, d=tb.w; int rr=hh*12+q;
        float e1d = (d==0)?e1x:((d==1)?e1y:e1z);
        if(rr<64){ val = (float)W[64+rr]*S[rr]*e1d; }
        else if(rr<80){ int k=rr-64; val = (float)W[128+k]*V[k*3+d]*e0; }
        else{
          int k=rr-80;
          float ax=V[k*3], ay=V[k*3+1], az=V[k*3+2];
          float cx = ay*e1z - az*e1y;
          float cy = az*e1x - ax*e1z;
          float cz = ax*e1y - ay*e1x;
          val = (float)W[160+k]*((d==0)?cx:(d==1)?cy:cz)*0.7071067811865475f;
        }
      }
      vr[j] = (_Float16)val;
    }
  }
}

// ---------- K4: per-node softmax + aggregation (wave per node, no atomics) ----------
__global__ __launch_bounds__(256) void k_agg(
  const int* __restrict__ offs, const float* __restrict__ alphaC,
  const _Float16* __restrict__ value, float* __restrict__ agg, int N)
{
  int wid = threadIdx.x>>6, lane = threadIdx.x&63;
  int n = blockIdx.x*4 + wid;
  if(n>=N) return;
  int s0 = offs[n], s1 = offs[n+1];

  // per-lane element heads (lane<46 owns j=lane*8+r)
  int hh[8];
  #pragma unroll
  for(int r=0;r<8;r++){ int j=lane*8+r; hh[r] = (j*713)>>15; if(hh[r]>7) hh[r]=7; }

  // pass 1: per-head max (8 edges x 8 heads per round)
  float mx = -1e30f;
  int h8 = lane&7;
  for(int b = s0 + (lane>>3); b < s1; b += 8)
    mx = fmaxf(mx, alphaC[(size_t)b*8 + h8]);
  mx = fmaxf(mx, __shfl_xor(mx, 8));
  mx = fmaxf(mx, __shfl_xor(mx, 16));
  mx = fmaxf(mx, __shfl_xor(mx, 32));
  // lane h (h<8) now holds max for head h

  // pass 2: exp, den, weighted accumulate
  float acc[8];
  #pragma unroll
  for(int r=0;r<8;r++) acc[r]=0.f;
  float den = 0.f;
  for(int b=s0; b<s1; ++b){
    float ev = 0.f;
    if(lane<8) ev = __expf(alphaC[(size_t)b*8 + lane] - mx);
    den += ev;
    f16x8 pk = {};
    if(lane<46) pk = *(const f16x8*)(value + (size_t)b*VROW + lane*8);
    #pragma unroll
    for(int r=0;r<8;r++){
      float av = __shfl(ev, hh[r]);
      acc[r] += av * (float)pk[r];
    }
  }
  if(lane<46){
    float o[8];
    #pragma unroll
    for(int r=0;r<8;r++){
      float dn = __shfl(den, hh[r]);
      o[r] = acc[r] / (dn + 1e-9f);
    }
    float* dst = agg + (size_t)n*VROW + lane*8;
    *(float4*)dst       = make_float4(o[0],o[1],o[2],o[3]);
    *(float4*)(dst+4)   = make_float4(o[4],o[5],o[6],o[7]);
  }
}

// ---------- K5: output projections (64 nodes / block) ----------
__global__ __launch_bounds__(256) void k_proj(
  const float* __restrict__ agg,
  const float* __restrict__ pws, const float* __restrict__ pbs,
  const float* __restrict__ pwv, float* __restrict__ out, int N)
{
  __shared__ float sWs[80*64];
  __shared__ float sWv[96*16];
  __shared__ float sA[4][VROW];
  int t=threadIdx.x, wid=t>>6, lane=t&63;
  for(int i=t;i<80*64;i+=256) sWs[i]=pws[i];
  for(int i=t;i<96*16;i+=256) sWv[i]=pwv[i];
  __syncthreads();
  for(int itn=0; itn<16; ++itn){
    int n = blockIdx.x*64 + itn*4 + wid;
    if(n>=N) continue;
    const float* arow = agg + (size_t)n*VROW;
    float* A = sA[wid];
    for(int j=lane;j<VROW;j+=64) A[j] = arow[j];
    float o1 = pbs[lane];
    #pragma unroll 8
    for(int i=0;i<80;i++){
      int hh=i/10, c=i-hh*10;
      o1 += A[hh*46+c]*sWs[i*64+lane];
    }
    out[(size_t)n*112+lane]=o1;
    if(lane<48){
      int ee=lane/3, d=lane-ee*3; float o2=0.f;
      #pragma unroll 8
      for(int c=0;c<96;c++){
        int hh=c/12, q=c-hh*12;
        o2 += A[hh*46+10+q*3+d]*sWv[c*16+ee];
      }
      out[(size_t)n*112+64+lane]=o2;
    }
  }
}

extern "C" void kernel_launch(void* const* d_in, const int* in_sizes, int n_in,
                              void* d_out, int out_size, void* d_ws, size_t ws_size,
                              hipStream_t stream)
{
  const int N = in_sizes[0]/112;
  const int E = in_sizes[1];
  const float* ni    = (const float*)d_in[0];
  const int*   esrc  = (const int*)d_in[1];
  const int*   edst  = (const int*)d_in[2];
  const float* eattr = (const float*)d_in[3];
  const float* escal = (const float*)d_in[4];
  const float* wss   = (const float*)d_in[5];
  const float* wsv   = (const float*)d_in[6];
  const float* wds   = (const float*)d_in[7];
  const float* wdv   = (const float*)d_in[8];
  const float* rw1   = (const float*)d_in[9];
  const float* rb1   = (const float*)d_in[10];
  const float* rw2   = (const float*)d_in[11];
  const float* rb2   = (const float*)d_in[12];
  const float* adot  = (const float*)d_in[13];
  const float* pws   = (const float*)d_in[14];
  const float* pbs   = (const float*)d_in[15];
  const float* pwv   = (const float*)d_in[16];
  float* out = (float*)d_out;

  char* ws = (char*)d_ws;
  size_t off = 0;
  auto alloc = [&](size_t bytes)->void*{
    void* p = ws + off;
    off = (off + bytes + 255) & ~(size_t)255;
    return p;
  };
  float*    xs_s  = (float*)   alloc((size_t)N*64*4);
  float*    xs_d  = (float*)   alloc((size_t)N*64*4);
  float*    xv_s  = (float*)   alloc((size_t)N*48*4);
  float*    xv_d  = (float*)   alloc((size_t)N*48*4);
  _Float16* wbuf  = (_Float16*)alloc((size_t)E*WST*2);   // dead after k_geo
  _Float16* value = (_Float16*)alloc((size_t)E*VROW*2);
  float*    alphaC= (float*)   alloc((size_t)E*8*4);
  int*      pos_of= (int*)     alloc((size_t)E*4);
  int*      deg   = (int*)     alloc((size_t)N*4);
  int*      offs  = (int*)     alloc((size_t)(N+1)*4);
  int*      cur   = (int*)     alloc((size_t)N*4);
  float*    agg   = (float*)wbuf;                         // alias: agg (73.6MB) <= wbuf (147MB)

  hipMemsetAsync(deg, 0, (size_t)N*4, stream);

  k_node<<<(N+63)/64, 256, 0, stream>>>(ni, wss, wsv, wds, wdv, xs_s, xs_d, xv_s, xv_d, N);
  k_deg<<<(E+255)/256, 256, 0, stream>>>(edst, deg, E);
  k_scan<<<1, 256, 0, stream>>>(deg, offs, cur, N);
  k_fill<<<(E+255)/256, 256, 0, stream>>>(edst, cur, pos_of, E);

  k_mlp<<<512, 256, 0, stream>>>(escal, rw1, rb1, rw2, rb2, wbuf, E);

  k_geo<<<2048, 256, 0, stream>>>(esrc, edst, eattr, wbuf, adot,
        xs_s, xs_d, xv_s, xv_d, pos_of, value, alphaC, E);

  k_agg<<<(N+3)/4, 256, 0, stream>>>(offs, alphaC, value, agg, N);

  k_proj<<<(N+63)/64, 256, 0, stream>>>(agg, pws, pbs, pwv, out, N);
}

// Round 5
// 810.893 us; speedup vs baseline: 2.3416x; 1.2212x over previous
//
#include <hip/hip_runtime.h>
#include <hip/hip_bf16.h>

#define VROW 368      // value/agg row: [w1s 192 | w2v 48 | cross 48 | sc 80]
#define WST  184      // wbuf row stride in f16 (176 + 8 pad)

typedef __attribute__((ext_vector_type(8))) short bf16x8;
typedef __attribute__((ext_vector_type(4))) float f32x4;
typedef __attribute__((ext_vector_type(8))) _Float16 f16x8;

__device__ inline ushort f2bf(float f){
  union { __hip_bfloat16 b; ushort u; } v;
  v.b = __float2bfloat16(f);
  return v.u;
}

// ---------- K1: node transforms (64 nodes / block) ----------
__global__ __launch_bounds__(256) void k_node(
  const float* __restrict__ ni,
  const float* __restrict__ wss, const float* __restrict__ wsv,
  const float* __restrict__ wds, const float* __restrict__ wdv,
  float* __restrict__ xs_s, float* __restrict__ xs_d,
  float* __restrict__ xv_s, float* __restrict__ xv_d, int N)
{
  __shared__ float sW0[64*64], sW1[64*64];
  __shared__ float sV0[256], sV1[256];
  __shared__ float sRow[4][112];
  int t = threadIdx.x, wid = t>>6, lane = t&63;
  for(int i=t;i<4096;i+=256){ sW0[i]=wss[i]; sW1[i]=wds[i]; }
  if(t<256){ sV0[t]=wsv[t]; sV1[t]=wdv[t]; }
  __syncthreads();
  for(int itn=0; itn<16; ++itn){
    int node = blockIdx.x*64 + itn*4 + wid;
    if(node>=N) continue;
    const float* row = ni + (size_t)node*112;
    if(lane<56) ((float2*)sRow[wid])[lane] = ((const float2*)row)[lane];
    float* r = sRow[wid];
    float a0=0.f, a1=0.f;
    #pragma unroll 8
    for(int k=0;k<64;k++){ float x=r[k]; a0+=x*sW0[k*64+lane]; a1+=x*sW1[k*64+lane]; }
    xs_s[(size_t)node*64+lane]=a0; xs_d[(size_t)node*64+lane]=a1;
    if(lane<48){
      int e_=lane/3, d_=lane-e_*3; float b0=0.f, b1=0.f;
      #pragma unroll
      for(int c=0;c<16;c++){ float x=r[64+c*3+d_]; b0+=x*sV0[c*16+e_]; b1+=x*sV1[c*16+e_]; }
      xv_s[(size_t)node*48+lane]=b0; xv_d[(size_t)node*48+lane]=b1;
    }
  }
}

// ---------- CSR build ----------
__global__ void k_deg(const int* __restrict__ edst, int* __restrict__ deg, int E){
  int e = blockIdx.x*256 + threadIdx.x;
  if(e<E) atomicAdd(&deg[edst[e]], 1);
}

__global__ __launch_bounds__(256) void k_scan(
  const int* __restrict__ deg, int* __restrict__ offs, int* __restrict__ cur, int N)
{
  __shared__ int sb[256];
  __shared__ int srun;
  int t = threadIdx.x;
  if(t==0) srun = 0;
  __syncthreads();
  for(int base=0; base<N; base+=256){
    int i = base + t;
    int x = (i<N) ? deg[i] : 0;
    sb[t] = x;
    __syncthreads();
    int v = x;
    #pragma unroll
    for(int o=1;o<256;o<<=1){
      int u = (t>=o) ? sb[t-o] : 0;
      __syncthreads();
      v += u; sb[t] = v;
      __syncthreads();
    }
    int run = srun;
    if(i<N){ int ex = run + v - x; offs[i]=ex; cur[i]=ex; }
    __syncthreads();
    if(t==255) srun = run + v;
    __syncthreads();
  }
  if(t==0) offs[N] = srun;
}

__global__ void k_fill(const int* __restrict__ edst, int* __restrict__ cur,
                       int* __restrict__ pos_of, int E){
  int e = blockIdx.x*256 + threadIdx.x;
  if(e<E) pos_of[e] = atomicAdd(&cur[edst[e]], 1);
}

// ---------- K2: radial MLP (pure MFMA GEMM pipeline) ----------
__global__ __launch_bounds__(256) void k_mlp(
  const float* __restrict__ escal,
  const float* __restrict__ w1, const float* __restrict__ b1,
  const float* __restrict__ w2, const float* __restrict__ b2,
  _Float16* __restrict__ wbuf, int E)
{
  __shared__ __align__(16) ushort sW1t[64*136];
  __shared__ __align__(16) ushort sW2t[176*72];
  __shared__ __align__(16) ushort ubuf[4][16*WST];
  int t = threadIdx.x, wid = t>>6, lane = t&63;
  int r16 = lane&15, g = lane>>4;

  for(int i=t;i<128*64;i+=256){ int k=i>>6, n=i&63; sW1t[n*136+k]=f2bf(w1[i]); }
  for(int i=t;i<64*176;i+=256){ int k=i/176, n=i-k*176; sW2t[n*72+k]=f2bf(w2[i]); }
  __syncthreads();

  float b1v[4], b2v[11];
  #pragma unroll
  for(int nt=0;nt<4;nt++) b1v[nt]=b1[nt*16+r16];
  #pragma unroll
  for(int s=0;s<11;s++) b2v[s]=b2[s*16+r16];

  ushort* ub = ubuf[wid];
  _Float16* wsb = (_Float16*)ub;

  int ntiles = (E+15)>>4;
  int nw = gridDim.x*4;

  for(int wt = blockIdx.x*4+wid; wt < ntiles; wt += nw){
    int ebase = wt*16;
    int erow = ebase + r16; if(erow >= E) erow = E-1;

    f32x4 acc[4];
    #pragma unroll
    for(int nt=0;nt<4;nt++) acc[nt]=(f32x4){0,0,0,0};
    #pragma unroll
    for(int ks=0;ks<4;ks++){
      const float* p = escal + (size_t)erow*128 + ks*32 + g*8;
      float4 va = *(const float4*)p;
      float4 vb = *(const float4*)(p+4);
      bf16x8 af;
      af[0]=(short)f2bf(va.x); af[1]=(short)f2bf(va.y);
      af[2]=(short)f2bf(va.z); af[3]=(short)f2bf(va.w);
      af[4]=(short)f2bf(vb.x); af[5]=(short)f2bf(vb.y);
      af[6]=(short)f2bf(vb.z); af[7]=(short)f2bf(vb.w);
      #pragma unroll
      for(int nt=0;nt<4;nt++){
        bf16x8 bf = *(const bf16x8*)&sW1t[(nt*16+r16)*136 + ks*32 + g*8];
        acc[nt] = __builtin_amdgcn_mfma_f32_16x16x32_bf16(af,bf,acc[nt],0,0,0);
      }
    }

    #pragma unroll
    for(int nt=0;nt<4;nt++)
      #pragma unroll
      for(int q=0;q<4;q++) acc[nt][q] += b1v[nt];
    #pragma unroll
    for(int q=0;q<4;q++){
      float s = acc[0][q]+acc[1][q]+acc[2][q]+acc[3][q];
      float ss = acc[0][q]*acc[0][q]+acc[1][q]*acc[1][q]+acc[2][q]*acc[2][q]+acc[3][q]*acc[3][q];
      #pragma unroll
      for(int o=1;o<16;o<<=1){ s += __shfl_xor(s,o); ss += __shfl_xor(ss,o); }
      float m = s*(1.f/64.f);
      float var = ss*(1.f/64.f) - m*m;
      float inv = rsqrtf(var + 1e-5f);
      int rr = g*4+q;
      #pragma unroll
      for(int nt=0;nt<4;nt++){
        float xn = (acc[nt][q]-m)*inv;
        float h = xn/(1.f+__expf(-xn));
        ub[rr*72 + nt*16 + r16] = f2bf(h);
      }
    }

    bf16x8 af2[2];
    af2[0] = *(const bf16x8*)&ub[r16*72 + 0*32 + g*8];
    af2[1] = *(const bf16x8*)&ub[r16*72 + 1*32 + g*8];
    f32x4 c2[11];
    #pragma unroll
    for(int s=0;s<11;s++) c2[s]=(f32x4){0,0,0,0};
    #pragma unroll
    for(int ks=0;ks<2;ks++){
      #pragma unroll
      for(int s=0;s<11;s++){
        bf16x8 bf = *(const bf16x8*)&sW2t[(s*16+r16)*72 + ks*32 + g*8];
        c2[s] = __builtin_amdgcn_mfma_f32_16x16x32_bf16(af2[ks],bf,c2[s],0,0,0);
      }
    }
    #pragma unroll
    for(int s=0;s<11;s++){
      int col = s*16 + r16;
      #pragma unroll
      for(int q=0;q<4;q++){
        wsb[(g*4+q)*WST + col] = (_Float16)(c2[s][q] + b2v[s]);
      }
    }
    int rows = E - ebase; if(rows > 16) rows = 16;
    int nf4 = rows*(WST/8);
    float4* dst = (float4*)(wbuf + (size_t)ebase*WST);
    const float4* srcv = (const float4*)ub;
    for(int i=lane; i<nf4; i+=64) dst[i] = srcv[i];
  }
}

// ---------- K3: geometric phase (uniform write phases, CSR order) ----------
__global__ __launch_bounds__(256) void k_geo(
  const int* __restrict__ esrc, const int* __restrict__ edst,
  const float* __restrict__ eattr, const _Float16* __restrict__ wbuf,
  const float* __restrict__ adot,
  const float* __restrict__ xs_s, const float* __restrict__ xs_d,
  const float* __restrict__ xv_s, const float* __restrict__ xv_d,
  const int* __restrict__ pos_of,
  _Float16* __restrict__ value, float* __restrict__ alphaC, int E)
{
  __shared__ float sAdot[80];
  __shared__ uchar2 sT3[192];          // i -> (i/3, i%3)
  __shared__ __align__(16) _Float16 sW[4][184];
  __shared__ float sV[4][48];
  __shared__ float sWS1[4][64];
  __shared__ float sW2E[4][16];
  __shared__ float sP[4][80];
  __shared__ float sE1[4][4];
  int t = threadIdx.x, wid = t>>6, lane = t&63;
  if(t<80) sAdot[t]=adot[t];
  for(int i=t;i<192;i+=256){ int r=i/3; sT3[i]=make_uchar2((unsigned char)r,(unsigned char)(i-3*r)); }
  __syncthreads();

  _Float16* W = sW[wid];
  float* V = sV[wid];
  float* WS1 = sWS1[wid];
  float* W2E = sW2E[wid];
  float* P = sP[wid];
  float* E1 = sE1[wid];
  int nw = gridDim.x*4;
  const float inv_s3 = 0.5773502691896258f, inv_s2 = 0.7071067811865475f;

  for(int e = blockIdx.x*4+wid; e < E; e += nw){
    int p = pos_of[e], si = esrc[e], di = edst[e];
    float4 ea = *(const float4*)&eattr[(size_t)e*4];
    float e0=ea.x, e1x=ea.y, e1y=ea.z, e1z=ea.w;
    if(lane<23) ((float4*)W)[lane] = ((const float4*)(wbuf + (size_t)e*WST))[lane];
    if(lane==0){ E1[0]=e1x; E1[1]=e1y; E1[2]=e1z; }
    float S = xs_s[(size_t)si*64+lane] + xs_d[(size_t)di*64+lane];
    if(lane<48) V[lane] = xv_s[(size_t)si*48+lane] + xv_d[(size_t)di*48+lane];
    float wl  = (float)W[lane];
    float w1l = (float)W[64+lane];
    WS1[lane] = w1l*S;
    if(lane<16) W2E[lane] = (float)W[128+lane]*e0;

    _Float16* vr = value + (size_t)p*VROW;

    // sc region [288..368): out_s, plus smooth-leaky products (wave-parallel exp)
    float sc = wl*S*e0;
    vr[288+lane] = (_Float16)sc;
    {
      float sg = 1.f/(1.f+__expf(-sc));
      P[lane] = sc*(0.2f + 0.8f*sg)*sAdot[lane];
    }
    if(lane<16){
      float vd = V[lane*3]*e1x + V[lane*3+1]*e1y + V[lane*3+2]*e1z;
      float sc2 = (float)W[144+lane]*vd*inv_s3;
      vr[352+lane] = (_Float16)sc2;
      float sg = 1.f/(1.f+__expf(-sc2));
      P[64+lane] = sc2*(0.2f + 0.8f*sg)*sAdot[64+lane];
    }
    if(lane<8){
      float a = P[lane*10];
      #pragma unroll
      for(int c=1;c<10;c++) a += P[lane*10+c];
      alphaC[(size_t)p*8+lane] = a;
    }

    // w1s region [0..192): element i=r*3+d -> W[64+r]*S[r]*e1[d]
    #pragma unroll
    for(int c3=0;c3<3;c3++){
      int i = c3*64 + lane;
      uchar2 rd = sT3[i];
      vr[i] = (_Float16)(WS1[rd.x]*E1[rd.y]);
    }
    // w2v [192..240) + cross [240..288): lanes 0..47, i=k*3+d
    if(lane<48){
      uchar2 rd = sT3[lane];
      int k = rd.x, d = rd.y;
      vr[192+lane] = (_Float16)(W2E[k]*V[lane]);
      int d1 = (d==2)?0:(d+1);
      int d2 = (d==0)?2:(d-1);
      float cr = V[3*k+d1]*E1[d2] - V[3*k+d2]*E1[d1];
      vr[240+lane] = (_Float16)((float)W[160+k]*cr*inv_s2);
    }
  }
}

// ---------- K4: per-node softmax + aggregation (wave per node, no atomics) ----------
__global__ __launch_bounds__(256) void k_agg(
  const int* __restrict__ offs, const float* __restrict__ alphaC,
  const _Float16* __restrict__ value, float* __restrict__ agg, int N)
{
  int wid = threadIdx.x>>6, lane = threadIdx.x&63;
  int n = blockIdx.x*4 + wid;
  if(n>=N) return;
  int s0 = offs[n], s1 = offs[n+1];

  // each lane<46 owns j = lane*8 + r; regions at 192/240/288 are 8-aligned,
  // so the 8 elements span at most 2 heads: h0 (first) / h1 (last).
  int h0=0, h1=0; unsigned msk=0;
  if(lane<46){
    #pragma unroll
    for(int r=0;r<8;r++){
      int j = lane*8 + r;
      int h;
      if(j<192)       h = j/36;                 // ch=j/3, head=ch/12
      else if(j<240)  h = (64 + (j-192)/3)/12;
      else if(j<288)  h = (80 + (j-240)/3)/12;
      else            h = (j-288)/10;
      if(r==0) h0=h;
      h1=h;
      if(h!=h0) msk |= (1u<<r);
    }
  }

  // pass 1: per-head max
  float mx = -1e30f;
  int h8 = lane&7;
  for(int b = s0 + (lane>>3); b < s1; b += 8)
    mx = fmaxf(mx, alphaC[(size_t)b*8 + h8]);
  mx = fmaxf(mx, __shfl_xor(mx, 8));
  mx = fmaxf(mx, __shfl_xor(mx, 16));
  mx = fmaxf(mx, __shfl_xor(mx, 32));

  // pass 2: exp, den, weighted accumulate
  float acc[8];
  #pragma unroll
  for(int r=0;r<8;r++) acc[r]=0.f;
  float den = 0.f;
  for(int b=s0; b<s1; ++b){
    float ev = (lane<8) ? __expf(alphaC[(size_t)b*8 + lane] - mx) : 0.f;
    den += ev;
    f16x8 pk = {};
    if(lane<46) pk = *(const f16x8*)(value + (size_t)b*VROW + lane*8);
    float av0 = __shfl(ev, h0), av1 = __shfl(ev, h1);
    #pragma unroll
    for(int r=0;r<8;r++){
      float av = (msk>>r & 1u) ? av1 : av0;
      acc[r] += av * (float)pk[r];
    }
  }
  float dn0 = __shfl(den, h0), dn1 = __shfl(den, h1);
  if(lane<46){
    float o[8];
    #pragma unroll
    for(int r=0;r<8;r++){
      float dn = (msk>>r & 1u) ? dn1 : dn0;
      o[r] = acc[r] / (dn + 1e-9f);
    }
    float* dst = agg + (size_t)n*VROW + lane*8;
    *(float4*)dst     = make_float4(o[0],o[1],o[2],o[3]);
    *(float4*)(dst+4) = make_float4(o[4],o[5],o[6],o[7]);
  }
}

// ---------- K5: output projections (64 nodes / block) ----------
__global__ __launch_bounds__(256) void k_proj(
  const float* __restrict__ agg,
  const float* __restrict__ pws, const float* __restrict__ pbs,
  const float* __restrict__ pwv, float* __restrict__ out, int N)
{
  __shared__ float sWs[80*64];
  __shared__ float sWv[96*16];
  __shared__ ushort sBv[96];
  __shared__ float sA[4][VROW];
  int t=threadIdx.x, wid=t>>6, lane=t&63;
  for(int i=t;i<80*64;i+=256) sWs[i]=pws[i];
  for(int i=t;i<96*16;i+=256) sWv[i]=pwv[i];
  for(int c=t;c<96;c+=256){
    int base = (c<64) ? c*3 : (c<80) ? 192+(c-64)*3 : 240+(c-80)*3;
    sBv[c] = (ushort)base;
  }
  __syncthreads();
  for(int itn=0; itn<16; ++itn){
    int n = blockIdx.x*64 + itn*4 + wid;
    if(n>=N) continue;
    const float* arow = agg + (size_t)n*VROW;
    float* A = sA[wid];
    for(int j=lane;j<VROW;j+=64) A[j] = arow[j];
    float o1 = pbs[lane];
    #pragma unroll 8
    for(int i=0;i<80;i++) o1 += A[288+i]*sWs[i*64+lane];
    out[(size_t)n*112+lane]=o1;
    if(lane<48){
      int ee=lane/3, d=lane-ee*3; float o2=0.f;
      #pragma unroll 8
      for(int c=0;c<96;c++) o2 += A[sBv[c]+d]*sWv[c*16+ee];
      out[(size_t)n*112+64+lane]=o2;
    }
  }
}

extern "C" void kernel_launch(void* const* d_in, const int* in_sizes, int n_in,
                              void* d_out, int out_size, void* d_ws, size_t ws_size,
                              hipStream_t stream)
{
  const int N = in_sizes[0]/112;
  const int E = in_sizes[1];
  const float* ni    = (const float*)d_in[0];
  const int*   esrc  = (const int*)d_in[1];
  const int*   edst  = (const int*)d_in[2];
  const float* eattr = (const float*)d_in[3];
  const float* escal = (const float*)d_in[4];
  const float* wss   = (const float*)d_in[5];
  const float* wsv   = (const float*)d_in[6];
  const float* wds   = (const float*)d_in[7];
  const float* wdv   = (const float*)d_in[8];
  const float* rw1   = (const float*)d_in[9];
  const float* rb1   = (const float*)d_in[10];
  const float* rw2   = (const float*)d_in[11];
  const float* rb2   = (const float*)d_in[12];
  const float* adot  = (const float*)d_in[13];
  const float* pws   = (const float*)d_in[14];
  const float* pbs   = (const float*)d_in[15];
  const float* pwv   = (const float*)d_in[16];
  float* out = (float*)d_out;

  char* ws = (char*)d_ws;
  size_t off = 0;
  auto alloc = [&](size_t bytes)->void*{
    void* p = ws + off;
    off = (off + bytes + 255) & ~(size_t)255;
    return p;
  };
  float*    xs_s  = (float*)   alloc((size_t)N*64*4);
  float*    xs_d  = (float*)   alloc((size_t)N*64*4);
  float*    xv_s  = (float*)   alloc((size_t)N*48*4);
  float*    xv_d  = (float*)   alloc((size_t)N*48*4);
  _Float16* wbuf  = (_Float16*)alloc((size_t)E*WST*2);   // dead after k_geo
  _Float16* value = (_Float16*)alloc((size_t)E*VROW*2);
  float*    alphaC= (float*)   alloc((size_t)E*8*4);
  int*      pos_of= (int*)     alloc((size_t)E*4);
  int*      deg   = (int*)     alloc((size_t)N*4);
  int*      offs  = (int*)     alloc((size_t)(N+1)*4);
  int*      cur   = (int*)     alloc((size_t)N*4);
  float*    agg   = (float*)wbuf;                         // alias: agg (73.6MB) <= wbuf (147MB)

  hipMemsetAsync(deg, 0, (size_t)N*4, stream);

  k_node<<<(N+63)/64, 256, 0, stream>>>(ni, wss, wsv, wds, wdv, xs_s, xs_d, xv_s, xv_d, N);
  k_deg<<<(E+255)/256, 256, 0, stream>>>(edst, deg, E);
  k_scan<<<1, 256, 0, stream>>>(deg, offs, cur, N);
  k_fill<<<(E+255)/256, 256, 0, stream>>>(edst, cur, pos_of, E);

  k_mlp<<<512, 256, 0, stream>>>(escal, rw1, rb1, rw2, rb2, wbuf, E);

  k_geo<<<2048, 256, 0, stream>>>(esrc, edst, eattr, wbuf, adot,
        xs_s, xs_d, xv_s, xv_d, pos_of, value, alphaC, E);

  k_agg<<<(N+3)/4, 256, 0, stream>>>(offs, alphaC, value, agg, N);

  k_proj<<<(N+63)/64, 256, 0, stream>>>(agg, pws, pbs, pwv, out, N);
}